// Round 9
// baseline (682.479 us; speedup 1.0000x reference)
//
#include <hip/hip_runtime.h>

#define S_ 2048
#define C_ 128
#define B_ 4
#define H_ 8
#define D_ 64

typedef __attribute__((ext_vector_type(8))) short bf16x8;
typedef __attribute__((ext_vector_type(4))) float f32x4;

__device__ inline unsigned short f2bf(float f) {
    union { float f; unsigned int u; } c; c.f = f;
    unsigned int u = c.u;
    unsigned int r = (u + 0x7FFFu + ((u >> 16) & 1u)) >> 16;
    return (unsigned short)r;
}
__device__ inline float bf2f(unsigned short s) {
    union { unsigned int u; float f; } c; c.u = ((unsigned int)s) << 16;
    return c.f;
}

// ---------------- prep: x->bf16 (float4), weights -> packed bf16, w1 -> w1T4 ----------------
__global__ __launch_bounds__(256) void prep_kernel(
    const float* __restrict__ x,
    const float* __restrict__ wq, const float* __restrict__ wk,
    const float* __restrict__ wv, const float* __restrict__ w1,
    unsigned short* __restrict__ xh,
    unsigned short* __restrict__ wPackQ, unsigned short* __restrict__ wPackK,
    unsigned short* __restrict__ wPackV, float* __restrict__ w1T4)
{
    int idx = blockIdx.x * 256 + threadIdx.x;
    if (idx < 262144) {                        // x: 4 elements per thread
        float4 v = *(const float4*)&x[idx * 4];
        ushort4 o;
        o.x = f2bf(v.x); o.y = f2bf(v.y); o.z = f2bf(v.z); o.w = f2bf(v.w);
        *(ushort4*)&xh[idx * 4] = o;
    } else if (idx < 458752) {                 // wPackQ: i = t*65536 + o*128 + c
        int i = idx - 262144;
        int t = i >> 16, r = i & 65535;
        int o = r >> 7, c = r & 127;
        wPackQ[i] = f2bf(wq[o * 384 + c * 3 + t]);
    } else if (idx < 655360) {
        int i = idx - 458752;
        int t = i >> 16, r = i & 65535;
        int o = r >> 7, c = r & 127;
        wPackK[i] = f2bf(wk[o * 384 + c * 3 + t]);
    } else if (idx < 720896) {
        int i = idx - 655360;
        wPackV[i] = f2bf(wv[i]);
    } else if (idx < 753664) {
        int i = idx - 720896;
        int jj = i & 3, d = (i >> 2) & 63, jb = i >> 8;
        w1T4[i] = w1[d * 512 + jb * 4 + jj];
    }
}

// ---------------- QKV projection via bf16 MFMA (Q,K,V fused per block) ----------------
// Q is scaled by 0.125 * log2(e) so attention can use exp2 directly.
__global__ __launch_bounds__(256) void qkv_kernel(
    const unsigned short* __restrict__ xh,
    const unsigned short* __restrict__ wPackQ, const unsigned short* __restrict__ wPackK,
    const unsigned short* __restrict__ wPackV,
    const float* __restrict__ bq, const float* __restrict__ bk,
    const float* __restrict__ bv,
    unsigned short* __restrict__ Qh, unsigned short* __restrict__ Kh,
    unsigned short* __restrict__ VhT)
{
    __shared__ __align__(16) short xs[130 * 136];
    __shared__ __align__(16) short ws[64 * 136];

    int s0 = blockIdx.x * 128;
    int h = blockIdx.y;
    int b = blockIdx.z;
    int bh = b * H_ + h;
    int tid = threadIdx.x;
    int w = tid >> 6;
    int lane = tid & 63;
    int col = lane & 15;
    int quad = lane >> 4;

    for (int i = tid; i < 2080; i += 256) {
        int row = i >> 4, c8 = (i & 15) << 3;
        int s = s0 - 2 + row;
        uint4 v = {0u, 0u, 0u, 0u};
        if (s >= 0) v = *(const uint4*)&xh[((long)b * S_ + s) * C_ + c8];
        *(uint4*)&xs[row * 136 + c8] = v;
    }

    for (int sec = 0; sec < 3; sec++) {
        const unsigned short* wsel = (sec == 0) ? wPackQ : (sec == 1) ? wPackK : wPackV;
        int tlo = (sec == 2) ? 2 : 0;

        f32x4 acc[2][4];
        #pragma unroll
        for (int rt = 0; rt < 2; rt++)
            #pragma unroll
            for (int nt = 0; nt < 4; nt++) acc[rt][nt] = (f32x4){0.f, 0.f, 0.f, 0.f};

        for (int t = tlo; t < 3; t++) {
            if (!(sec == 0 && t == 0)) __syncthreads();
            long wbase = (sec == 2) ? ((long)h * 8192)
                                    : ((long)t * 65536 + (long)h * 8192);
            for (int i = tid; i < 1024; i += 256) {
                int row = i >> 4, c8 = (i & 15) << 3;
                *(uint4*)&ws[row * 136 + c8] = *(const uint4*)&wsel[wbase + row * 128 + c8];
            }
            __syncthreads();

            #pragma unroll
            for (int kc = 0; kc < 4; kc++) {
                int ko = kc * 32 + quad * 8;
                bf16x8 a0 = *(const bf16x8*)&xs[(w * 32 + col + t) * 136 + ko];
                bf16x8 a1 = *(const bf16x8*)&xs[(w * 32 + 16 + col + t) * 136 + ko];
                #pragma unroll
                for (int nt = 0; nt < 4; nt++) {
                    bf16x8 bfr = *(const bf16x8*)&ws[(nt * 16 + col) * 136 + ko];
                    acc[0][nt] = __builtin_amdgcn_mfma_f32_16x16x32_bf16(a0, bfr, acc[0][nt], 0, 0, 0);
                    acc[1][nt] = __builtin_amdgcn_mfma_f32_16x16x32_bf16(a1, bfr, acc[1][nt], 0, 0, 0);
                }
            }
        }

        if (sec == 0) {
            #pragma unroll
            for (int nt = 0; nt < 4; nt++) {
                float bias = bq[h * 64 + nt * 16 + col];
                #pragma unroll
                for (int rt = 0; rt < 2; rt++)
                    #pragma unroll
                    for (int r = 0; r < 4; r++) {
                        int s = s0 + w * 32 + rt * 16 + quad * 4 + r;
                        Qh[((long)bh * S_ + s) * D_ + nt * 16 + col] =
                            f2bf((acc[rt][nt][r] + bias) * 0.18033688011112042f); // 0.125*log2(e)
                    }
            }
        } else if (sec == 1) {
            #pragma unroll
            for (int nt = 0; nt < 4; nt++) {
                float bias = bk[h * 64 + nt * 16 + col];
                #pragma unroll
                for (int rt = 0; rt < 2; rt++)
                    #pragma unroll
                    for (int r = 0; r < 4; r++) {
                        int s = s0 + w * 32 + rt * 16 + quad * 4 + r;
                        Kh[((long)bh * S_ + s) * D_ + nt * 16 + col] =
                            f2bf(acc[rt][nt][r] + bias);
                    }
            }
        } else {
            __syncthreads();
            #pragma unroll
            for (int nt = 0; nt < 4; nt++) {
                float bias = bv[h * 64 + nt * 16 + col];
                #pragma unroll
                for (int rt = 0; rt < 2; rt++)
                    #pragma unroll
                    for (int r = 0; r < 4; r++) {
                        int sl = w * 32 + rt * 16 + quad * 4 + r;
                        ws[(nt * 16 + col) * 136 + sl] =
                            (short)f2bf(fmaxf(acc[rt][nt][r] + bias, 0.f));
                    }
            }
            __syncthreads();
            for (int i = tid; i < 1024; i += 256) {
                int row = i >> 4, c8 = (i & 15) << 3;
                *(uint4*)&VhT[((long)bh * D_ + row) * S_ + s0 + c8] =
                    *(const uint4*)&ws[row * 136 + c8];
            }
        }
    }
}

// ---------------- fused flash attention, 128-row q-tiles ----------------
// Each block owns 128 q-rows (wave w: rows w*32..w*32+31, 2 row-groups).
// Every staged 64x64 K/V tile + every B-fragment ds_read now feeds 2x the
// MFMA work (ds_read:MFMA 1:2); staging bytes, barriers, loop fixed costs
// per flop halve vs the 64-row version. Grid 512 = 2 blocks/CU, fully
// resident. slot->(qt2,b) mapping keeps per-CU pair work constant under
// EITHER sequential-pair or round-robin-wrap scheduling:
//   qt2 = (s0^s5) ? 15-m : m ; b = 2*s5+s0  (pair-sums = 15 both ways).
#define PST 78
__global__ __launch_bounds__(256) void attn_kernel(
    const unsigned short* __restrict__ Qh, const unsigned short* __restrict__ Kh,
    const unsigned short* __restrict__ VhT, const int* __restrict__ length,
    float* __restrict__ score, float* __restrict__ out2)
{
    __shared__ __align__(16) short Kbuf[2][2][64 * 72]; // [half][K=0/V=1]
    __shared__ __align__(16) short Pfh[128 * PST];      // P bf16 [q][k] (wave-local)

    int idx = blockIdx.x;              // 512 blocks
    int xcd = idx & 7;
    int slot = idx >> 3;               // 0..63
    int s0b = slot & 1;
    int m   = (slot >> 1) & 15;
    int s5  = slot >> 5;
    int qt2 = (s0b ^ s5) ? (15 - m) : m;
    int b   = s5 * 2 + s0b;
    int h   = xcd;
    int bh  = b * 8 + h;
    int q0  = qt2 * 128;
    int ktmax = 2 * qt2 + 1;           // inclusive, 64-col K tiles
    int tid = threadIdx.x;
    int w = tid >> 6;
    int lane = tid & 63;
    int col = lane & 15;
    int quad = lane >> 4;
    int len = length[b];

    const unsigned short* Qb = Qh + (long)bh * S_ * D_;
    const unsigned short* Kb = Kh + (long)bh * S_ * D_;
    const unsigned short* Vtb = VhT + (long)bh * D_ * S_;
    float* scb = score + (long)bh * S_ * S_;

    // ---- full-block skip: all 128 query rows masked ----
    if (q0 >= len) {
        f32x4 z = (f32x4){0.f, 0.f, 0.f, 0.f};
        for (int kt2 = 0; kt2 < 32; kt2++) {
            #pragma unroll
            for (int it = 0; it < 8; it++) {
                int idx2 = tid + it * 256;
                int rr = idx2 >> 4, cc = idx2 & 15;
                __builtin_nontemporal_store(z,
                    (f32x4*)&scb[(long)(q0 + rr) * S_ + kt2 * 64 + cc * 4]);
            }
        }
        #pragma unroll
        for (int it = 0; it < 8; it++) {
            int idx2 = tid + it * 256;
            int rr = idx2 >> 4, cc = idx2 & 15;
            *(f32x4*)&out2[((long)(b * S_ + q0 + rr)) * 512 + h * 64 + cc * 4] = z;
        }
        return;
    }

    int srow_ = tid >> 2, sc16_ = (tid & 3) * 16;   // staging coords (64 rows)

    // Q A-fragments direct from global (wave-contiguous, one-time)
    bf16x8 aq[2][2];
    {
        int ar = q0 + w * 32 + col;
        aq[0][0] = *(const bf16x8*)&Qb[ar * D_ + quad * 8];
        aq[0][1] = *(const bf16x8*)&Qb[ar * D_ + 32 + quad * 8];
        aq[1][0] = *(const bf16x8*)&Qb[(ar + 16) * D_ + quad * 8];
        aq[1][1] = *(const bf16x8*)&Qb[(ar + 16) * D_ + 32 + quad * 8];
    }

    // ---- pass 1: l = sum(exp2(s')) per row, K double-buffered ----
    float lrun[2][4];
    #pragma unroll
    for (int rt = 0; rt < 2; rt++)
        #pragma unroll
        for (int r = 0; r < 4; r++) lrun[rt][r] = 0.f;

    {   // prologue: stage K tile 0
        *(uint4*)&Kbuf[0][0][srow_ * 72 + sc16_]     = *(const uint4*)&Kb[srow_ * D_ + sc16_];
        *(uint4*)&Kbuf[0][0][srow_ * 72 + sc16_ + 8] = *(const uint4*)&Kb[srow_ * D_ + sc16_ + 8];
    }
    __syncthreads();

    for (int kt = 0; kt <= ktmax; kt++) {
        int buf = kt & 1;
        if (kt < ktmax) {
            *(uint4*)&Kbuf[1 - buf][0][srow_ * 72 + sc16_] =
                *(const uint4*)&Kb[((kt + 1) * 64 + srow_) * D_ + sc16_];
            *(uint4*)&Kbuf[1 - buf][0][srow_ * 72 + sc16_ + 8] =
                *(const uint4*)&Kb[((kt + 1) * 64 + srow_) * D_ + sc16_ + 8];
        }

        f32x4 acc[2][4];
        #pragma unroll
        for (int rt = 0; rt < 2; rt++)
            #pragma unroll
            for (int n = 0; n < 4; n++) acc[rt][n] = (f32x4){0.f, 0.f, 0.f, 0.f};
        #pragma unroll
        for (int n = 0; n < 4; n++) {
            bf16x8 b0 = *(const bf16x8*)&Kbuf[buf][0][(n * 16 + col) * 72 + quad * 8];
            bf16x8 b1 = *(const bf16x8*)&Kbuf[buf][0][(n * 16 + col) * 72 + 32 + quad * 8];
            #pragma unroll
            for (int rt = 0; rt < 2; rt++) {
                acc[rt][n] = __builtin_amdgcn_mfma_f32_16x16x32_bf16(aq[rt][0], b0, acc[rt][n], 0, 0, 0);
                acc[rt][n] = __builtin_amdgcn_mfma_f32_16x16x32_bf16(aq[rt][1], b1, acc[rt][n], 0, 0, 0);
            }
        }
        if (kt >= 2 * qt2) {   // diagonal region (last two K tiles)
            #pragma unroll
            for (int n = 0; n < 4; n++) {
                int kk = kt * 64 + n * 16 + col;
                #pragma unroll
                for (int rt = 0; rt < 2; rt++)
                    #pragma unroll
                    for (int r = 0; r < 4; r++) {
                        int q = q0 + w * 32 + rt * 16 + quad * 4 + r;
                        if (kk > q) acc[rt][n][r] = -1.0e30f;
                    }
            }
        }
        #pragma unroll
        for (int rt = 0; rt < 2; rt++)
            #pragma unroll
            for (int r = 0; r < 4; r++) {
                lrun[rt][r] += exp2f(acc[rt][0][r]) + exp2f(acc[rt][1][r]) +
                               exp2f(acc[rt][2][r]) + exp2f(acc[rt][3][r]);
            }
        __syncthreads();
    }

    #pragma unroll
    for (int off = 1; off < 16; off <<= 1) {
        #pragma unroll
        for (int rt = 0; rt < 2; rt++)
            #pragma unroll
            for (int r = 0; r < 4; r++) lrun[rt][r] += __shfl_xor(lrun[rt][r], off, 64);
    }
    float linv[2][4];
    #pragma unroll
    for (int rt = 0; rt < 2; rt++)
        #pragma unroll
        for (int r = 0; r < 4; r++) linv[rt][r] = 1.0f / lrun[rt][r];

    // ---- pass 2: recompute logits, bf16 P, coalesced NT store, P@V ----
    f32x4 oacc[2][4];
    #pragma unroll
    for (int rt = 0; rt < 2; rt++)
        #pragma unroll
        for (int n = 0; n < 4; n++) oacc[rt][n] = (f32x4){0.f, 0.f, 0.f, 0.f};

    int rlo = lane >> 4;          // 0..3
    int c4 = (lane & 15) * 4;     // float offset in row

#define STAGE2(HALF, KT) do { \
    *(uint4*)&Kbuf[HALF][0][srow_ * 72 + sc16_] = \
        *(const uint4*)&Kb[((KT) * 64 + srow_) * D_ + sc16_]; \
    *(uint4*)&Kbuf[HALF][0][srow_ * 72 + sc16_ + 8] = \
        *(const uint4*)&Kb[((KT) * 64 + srow_) * D_ + sc16_ + 8]; \
    *(uint4*)&Kbuf[HALF][1][srow_ * 72 + sc16_] = \
        *(const uint4*)&Vtb[srow_ * S_ + (KT) * 64 + sc16_]; \
    *(uint4*)&Kbuf[HALF][1][srow_ * 72 + sc16_ + 8] = \
        *(const uint4*)&Vtb[srow_ * S_ + (KT) * 64 + sc16_ + 8]; \
} while (0)

#define TILE2(HALF, KT) do { \
    f32x4 acc[2][4]; \
    _Pragma("unroll") \
    for (int rt = 0; rt < 2; rt++) \
        _Pragma("unroll") \
        for (int n = 0; n < 4; n++) acc[rt][n] = (f32x4){0.f, 0.f, 0.f, 0.f}; \
    _Pragma("unroll") \
    for (int n = 0; n < 4; n++) { \
        bf16x8 b0 = *(const bf16x8*)&Kbuf[HALF][0][(n * 16 + col) * 72 + quad * 8]; \
        bf16x8 b1 = *(const bf16x8*)&Kbuf[HALF][0][(n * 16 + col) * 72 + 32 + quad * 8]; \
        _Pragma("unroll") \
        for (int rt = 0; rt < 2; rt++) { \
            acc[rt][n] = __builtin_amdgcn_mfma_f32_16x16x32_bf16(aq[rt][0], b0, acc[rt][n], 0, 0, 0); \
            acc[rt][n] = __builtin_amdgcn_mfma_f32_16x16x32_bf16(aq[rt][1], b1, acc[rt][n], 0, 0, 0); \
        } \
    } \
    bool diag = ((KT) >= 2 * qt2); \
    _Pragma("unroll") \
    for (int n = 0; n < 4; n++) { \
        int kk = (KT) * 64 + n * 16 + col; \
        _Pragma("unroll") \
        for (int rt = 0; rt < 2; rt++) \
            _Pragma("unroll") \
            for (int r = 0; r < 4; r++) { \
                int q = q0 + w * 32 + rt * 16 + quad * 4 + r; \
                float pv = exp2f(acc[rt][n][r]) * linv[rt][r]; \
                if (q >= len || (diag && kk > q)) pv = 0.f; \
                Pfh[(w * 32 + rt * 16 + quad * 4 + r) * PST + n * 16 + col] = (short)f2bf(pv); \
            } \
    } \
    bf16x8 pa[2][2]; \
    pa[0][0] = *(const bf16x8*)&Pfh[(w * 32 + col) * PST + quad * 8]; \
    pa[0][1] = *(const bf16x8*)&Pfh[(w * 32 + col) * PST + 32 + quad * 8]; \
    pa[1][0] = *(const bf16x8*)&Pfh[(w * 32 + 16 + col) * PST + quad * 8]; \
    pa[1][1] = *(const bf16x8*)&Pfh[(w * 32 + 16 + col) * PST + 32 + quad * 8]; \
    _Pragma("unroll") \
    for (int n = 0; n < 4; n++) { \
        bf16x8 vv0 = *(const bf16x8*)&Kbuf[HALF][1][(n * 16 + col) * 72 + quad * 8]; \
        bf16x8 vv1 = *(const bf16x8*)&Kbuf[HALF][1][(n * 16 + col) * 72 + 32 + quad * 8]; \
        _Pragma("unroll") \
        for (int rt = 0; rt < 2; rt++) { \
            oacc[rt][n] = __builtin_amdgcn_mfma_f32_16x16x32_bf16(pa[rt][0], vv0, oacc[rt][n], 0, 0, 0); \
            oacc[rt][n] = __builtin_amdgcn_mfma_f32_16x16x32_bf16(pa[rt][1], vv1, oacc[rt][n], 0, 0, 0); \
        } \
    } \
    _Pragma("unroll") \
    for (int j = 0; j < 8; j++) { \
        int row = w * 32 + j * 4 + rlo; \
        uint2 pk = *(const uint2*)&Pfh[row * PST + c4]; \
        f32x4 v; \
        v[0] = bf2f((unsigned short)(pk.x & 0xFFFFu)); \
        v[1] = bf2f((unsigned short)(pk.x >> 16)); \
        v[2] = bf2f((unsigned short)(pk.y & 0xFFFFu)); \
        v[3] = bf2f((unsigned short)(pk.y >> 16)); \
        __builtin_nontemporal_store(v, \
            (f32x4*)&scb[(long)(q0 + row) * S_ + (KT) * 64 + c4]); \
    } \
} while (0)

    STAGE2(0, 0);
    __syncthreads();
    {
        int kt = 0;
        while (true) {
            if (kt < ktmax) STAGE2(1, kt + 1);
            TILE2(0, kt);
            __syncthreads();
            kt++; if (kt > ktmax) break;
            if (kt < ktmax) STAGE2(0, kt + 1);
            TILE2(1, kt);
            __syncthreads();
            kt++; if (kt > ktmax) break;
        }
    }
#undef STAGE2
#undef TILE2

    // out2[b][s][h*64+dv]
    #pragma unroll
    for (int rt = 0; rt < 2; rt++)
        #pragma unroll
        for (int n = 0; n < 4; n++)
            #pragma unroll
            for (int r = 0; r < 4; r++) {
                int q = q0 + w * 32 + rt * 16 + quad * 4 + r;
                out2[((long)(b * S_ + q)) * 512 + h * 64 + n * 16 + col] = oacc[rt][n][r];
            }

    // zero the strictly-above-diagonal tiles (NT, coalesced)
    f32x4 z = (f32x4){0.f, 0.f, 0.f, 0.f};
    for (int kt2 = ktmax + 1; kt2 < 32; kt2++) {
        #pragma unroll
        for (int it = 0; it < 8; it++) {
            int idx2 = tid + it * 256;
            int rr = idx2 >> 4, cc = idx2 & 15;
            __builtin_nontemporal_store(z,
                (f32x4*)&scb[(long)(q0 + rr) * S_ + kt2 * 64 + cc * 4]);
        }
    }
}

// ---------------- MLP head (f32x4 dot on packed w1T4) ----------------
__global__ __launch_bounds__(256) void mlp_kernel(
    const float* __restrict__ out2, const float* __restrict__ w1T4,
    const float* __restrict__ b1, const float* __restrict__ w2,
    const float* __restrict__ b2, float* __restrict__ out3)
{
    __shared__ __align__(16) float xr[2048];
    int sg0 = blockIdx.x * 4;
    int tid = threadIdx.x;
    for (int i = tid; i < 512; i += 256)
        *(f32x4*)&xr[i * 4] = *(const f32x4*)&out2[(long)sg0 * 512 + i * 4];
    __syncthreads();

    int sl = tid >> 6, d = tid & 63;
    float acc = 0.f;
    #pragma unroll 4
    for (int jb = 0; jb < 128; jb++) {
        f32x4 xv = *(const f32x4*)&xr[sl * 512 + jb * 4];
        f32x4 wv = *(const f32x4*)&w1T4[jb * 256 + d * 4];
        acc += xv[0] * wv[0] + xv[1] * wv[1] + xv[2] * wv[2] + xv[3] * wv[3];
    }
    float hval = fmaxf(acc + b1[d], 0.f);
    float p = hval * w2[d];
    #pragma unroll
    for (int off = 32; off > 0; off >>= 1) p += __shfl_xor(p, off, 64);
    if (d == 0) out3[sg0 + sl] = p + b2[0];
}

// ---------------- launcher ----------------
extern "C" void kernel_launch(void* const* d_in, const int* in_sizes, int n_in,
                              void* d_out, int out_size, void* d_ws, size_t ws_size,
                              hipStream_t stream) {
    const float* x      = (const float*)d_in[0];
    const int*   length = (const int*)  d_in[1];
    const float* wq     = (const float*)d_in[2];
    const float* bq     = (const float*)d_in[3];
    const float* wk     = (const float*)d_in[4];
    const float* bk     = (const float*)d_in[5];
    const float* wv     = (const float*)d_in[6];
    const float* bv     = (const float*)d_in[7];
    const float* w1     = (const float*)d_in[8];
    const float* b1     = (const float*)d_in[9];
    const float* w2     = (const float*)d_in[10];
    const float* b2     = (const float*)d_in[11];

    float* out3  = (float*)d_out;
    float* score = (float*)d_out + 8192;   // (B,H,S,S) follows (B,S,1)

    float* ws  = (float*)d_ws;
    unsigned short* xh     = (unsigned short*)ws;  ws += 524288;
    unsigned short* wPackQ = (unsigned short*)ws;  ws += 98304;
    unsigned short* wPackK = (unsigned short*)ws;  ws += 98304;
    unsigned short* wPackV = (unsigned short*)ws;  ws += 32768;
    float* w1T4 = ws;  ws += 32768;
    unsigned short* Qh  = (unsigned short*)ws;  ws += 2097152;
    unsigned short* Kh  = (unsigned short*)ws;  ws += 2097152;
    unsigned short* VhT = (unsigned short*)ws;  ws += 2097152;
    float* o2  = ws;  ws += 4194304;

    hipLaunchKernelGGL(prep_kernel, dim3(2944), dim3(256), 0, stream,
                       x, wq, wk, wv, w1, xh, wPackQ, wPackK, wPackV, w1T4);
    hipLaunchKernelGGL(qkv_kernel, dim3(16, 8, 4), dim3(256), 0, stream,
                       xh, wPackQ, wPackK, wPackV, bq, bk, bv, Qh, Kh, VhT);
    hipLaunchKernelGGL(attn_kernel, dim3(512), dim3(256), 0, stream,
                       Qh, Kh, VhT, length, score, o2);
    hipLaunchKernelGGL(mlp_kernel, dim3(2048), dim3(256), 0, stream,
                       o2, w1T4, b1, w2, b2, out3);
}

// Round 10
// 674.981 us; speedup vs baseline: 1.0111x; 1.0111x over previous
//
#include <hip/hip_runtime.h>

#define S_ 2048
#define C_ 128
#define B_ 4
#define H_ 8
#define D_ 64

typedef __attribute__((ext_vector_type(8))) short bf16x8;
typedef __attribute__((ext_vector_type(4))) float f32x4;

__device__ inline unsigned short f2bf(float f) {
    union { float f; unsigned int u; } c; c.f = f;
    unsigned int u = c.u;
    unsigned int r = (u + 0x7FFFu + ((u >> 16) & 1u)) >> 16;
    return (unsigned short)r;
}
__device__ inline float bf2f(unsigned short s) {
    union { unsigned int u; float f; } c; c.u = ((unsigned int)s) << 16;
    return c.f;
}

// ---------------- prep: x->bf16, weights -> packed bf16, w1 -> w1T4, zero lbuf ----------------
__global__ __launch_bounds__(256) void prep_kernel(
    const float* __restrict__ x,
    const float* __restrict__ wq, const float* __restrict__ wk,
    const float* __restrict__ wv, const float* __restrict__ w1,
    unsigned short* __restrict__ xh,
    unsigned short* __restrict__ wPackQ, unsigned short* __restrict__ wPackK,
    unsigned short* __restrict__ wPackV, float* __restrict__ w1T4,
    float* __restrict__ lbuf)
{
    int idx = blockIdx.x * 256 + threadIdx.x;
    if (idx < 262144) {                        // x: 4 elements per thread
        float4 v = *(const float4*)&x[idx * 4];
        ushort4 o;
        o.x = f2bf(v.x); o.y = f2bf(v.y); o.z = f2bf(v.z); o.w = f2bf(v.w);
        *(ushort4*)&xh[idx * 4] = o;
    } else if (idx < 458752) {                 // wPackQ: i = t*65536 + o*128 + c
        int i = idx - 262144;
        int t = i >> 16, r = i & 65535;
        int o = r >> 7, c = r & 127;
        wPackQ[i] = f2bf(wq[o * 384 + c * 3 + t]);
    } else if (idx < 655360) {
        int i = idx - 458752;
        int t = i >> 16, r = i & 65535;
        int o = r >> 7, c = r & 127;
        wPackK[i] = f2bf(wk[o * 384 + c * 3 + t]);
    } else if (idx < 720896) {
        int i = idx - 655360;
        wPackV[i] = f2bf(wv[i]);
    } else if (idx < 753664) {
        int i = idx - 720896;
        int jj = i & 3, d = (i >> 2) & 63, jb = i >> 8;
        w1T4[i] = w1[d * 512 + jb * 4 + jj];
    } else if (idx < 819200) {                 // lbuf = 0 (32*2048 floats)
        lbuf[idx - 753664] = 0.f;
    }
}

// ---------------- QKV projection via bf16 MFMA (Q,K,V fused per block) ----------------
// Q is scaled by 0.125 * log2(e) so attention can use exp2 directly.
__global__ __launch_bounds__(256) void qkv_kernel(
    const unsigned short* __restrict__ xh,
    const unsigned short* __restrict__ wPackQ, const unsigned short* __restrict__ wPackK,
    const unsigned short* __restrict__ wPackV,
    const float* __restrict__ bq, const float* __restrict__ bk,
    const float* __restrict__ bv,
    unsigned short* __restrict__ Qh, unsigned short* __restrict__ Kh,
    unsigned short* __restrict__ VhT)
{
    __shared__ __align__(16) short xs[130 * 136];
    __shared__ __align__(16) short ws[64 * 136];

    int s0 = blockIdx.x * 128;
    int h = blockIdx.y;
    int b = blockIdx.z;
    int bh = b * H_ + h;
    int tid = threadIdx.x;
    int w = tid >> 6;
    int lane = tid & 63;
    int col = lane & 15;
    int quad = lane >> 4;

    for (int i = tid; i < 2080; i += 256) {
        int row = i >> 4, c8 = (i & 15) << 3;
        int s = s0 - 2 + row;
        uint4 v = {0u, 0u, 0u, 0u};
        if (s >= 0) v = *(const uint4*)&xh[((long)b * S_ + s) * C_ + c8];
        *(uint4*)&xs[row * 136 + c8] = v;
    }

    for (int sec = 0; sec < 3; sec++) {
        const unsigned short* wsel = (sec == 0) ? wPackQ : (sec == 1) ? wPackK : wPackV;
        int tlo = (sec == 2) ? 2 : 0;

        f32x4 acc[2][4];
        #pragma unroll
        for (int rt = 0; rt < 2; rt++)
            #pragma unroll
            for (int nt = 0; nt < 4; nt++) acc[rt][nt] = (f32x4){0.f, 0.f, 0.f, 0.f};

        for (int t = tlo; t < 3; t++) {
            if (!(sec == 0 && t == 0)) __syncthreads();
            long wbase = (sec == 2) ? ((long)h * 8192)
                                    : ((long)t * 65536 + (long)h * 8192);
            for (int i = tid; i < 1024; i += 256) {
                int row = i >> 4, c8 = (i & 15) << 3;
                *(uint4*)&ws[row * 136 + c8] = *(const uint4*)&wsel[wbase + row * 128 + c8];
            }
            __syncthreads();

            #pragma unroll
            for (int kc = 0; kc < 4; kc++) {
                int ko = kc * 32 + quad * 8;
                bf16x8 a0 = *(const bf16x8*)&xs[(w * 32 + col + t) * 136 + ko];
                bf16x8 a1 = *(const bf16x8*)&xs[(w * 32 + 16 + col + t) * 136 + ko];
                #pragma unroll
                for (int nt = 0; nt < 4; nt++) {
                    bf16x8 bfr = *(const bf16x8*)&ws[(nt * 16 + col) * 136 + ko];
                    acc[0][nt] = __builtin_amdgcn_mfma_f32_16x16x32_bf16(a0, bfr, acc[0][nt], 0, 0, 0);
                    acc[1][nt] = __builtin_amdgcn_mfma_f32_16x16x32_bf16(a1, bfr, acc[1][nt], 0, 0, 0);
                }
            }
        }

        if (sec == 0) {
            #pragma unroll
            for (int nt = 0; nt < 4; nt++) {
                float bias = bq[h * 64 + nt * 16 + col];
                #pragma unroll
                for (int rt = 0; rt < 2; rt++)
                    #pragma unroll
                    for (int r = 0; r < 4; r++) {
                        int s = s0 + w * 32 + rt * 16 + quad * 4 + r;
                        Qh[((long)bh * S_ + s) * D_ + nt * 16 + col] =
                            f2bf((acc[rt][nt][r] + bias) * 0.18033688011112042f); // 0.125*log2(e)
                    }
            }
        } else if (sec == 1) {
            #pragma unroll
            for (int nt = 0; nt < 4; nt++) {
                float bias = bk[h * 64 + nt * 16 + col];
                #pragma unroll
                for (int rt = 0; rt < 2; rt++)
                    #pragma unroll
                    for (int r = 0; r < 4; r++) {
                        int s = s0 + w * 32 + rt * 16 + quad * 4 + r;
                        Kh[((long)bh * S_ + s) * D_ + nt * 16 + col] =
                            f2bf(acc[rt][nt][r] + bias);
                    }
            }
        } else {
            __syncthreads();
            #pragma unroll
            for (int nt = 0; nt < 4; nt++) {
                float bias = bv[h * 64 + nt * 16 + col];
                #pragma unroll
                for (int rt = 0; rt < 2; rt++)
                    #pragma unroll
                    for (int r = 0; r < 4; r++) {
                        int sl = w * 32 + rt * 16 + quad * 4 + r;
                        ws[(nt * 16 + col) * 136 + sl] =
                            (short)f2bf(fmaxf(acc[rt][nt][r] + bias, 0.f));
                    }
            }
            __syncthreads();
            for (int i = tid; i < 1024; i += 256) {
                int row = i >> 4, c8 = (i & 15) << 3;
                *(uint4*)&VhT[((long)bh * D_ + row) * S_ + s0 + c8] =
                    *(const uint4*)&ws[row * 136 + c8];
            }
        }
    }
}

// ---------------- softmax denominators, massively parallel ----------------
// Pass 1 hoisted out of the attention critical path. Grid (qt=32, bh=32,
// chunk=8): each block does <=4 K-tiles of QK^T+exp2 with NO LDS and NO
// barriers (K frags direct from L2; 8K tiny blocks give the TLP the
// monolithic kernel lacked), lane-reduces, atomicAdds into lbuf[bh][q].
// Same MFMA fragments as pass 2 -> identical acc values; only the sum
// order changes (fp32 reassociation, far below tolerance).
__global__ __launch_bounds__(256) void lsum_kernel(
    const unsigned short* __restrict__ Qh, const unsigned short* __restrict__ Kh,
    const int* __restrict__ length, float* __restrict__ lbuf)
{
    int qt = blockIdx.x;
    int bh = blockIdx.y;
    int ck = blockIdx.z;
    int kt0 = ck * 4;
    if (kt0 > qt) return;
    int b = bh >> 3;
    int len = length[b];
    int q0 = qt * 64;
    if (q0 >= len) return;

    int tid = threadIdx.x;
    int w = tid >> 6, lane = tid & 63, col = lane & 15, quad = lane >> 4;
    const unsigned short* Qb = Qh + (long)bh * S_ * D_;
    const unsigned short* Kb = Kh + (long)bh * S_ * D_;

    int arow = w * 16 + col;
    bf16x8 aq0 = *(const bf16x8*)&Qb[(q0 + arow) * D_ + quad * 8];
    bf16x8 aq1 = *(const bf16x8*)&Qb[(q0 + arow) * D_ + 32 + quad * 8];

    float lrun[4];
    #pragma unroll
    for (int r = 0; r < 4; r++) lrun[r] = 0.f;

    int ktend = (kt0 + 3 < qt) ? kt0 + 3 : qt;
    for (int kt = kt0; kt <= ktend; kt++) {
        f32x4 acc[4];
        #pragma unroll
        for (int n = 0; n < 4; n++) acc[n] = (f32x4){0.f, 0.f, 0.f, 0.f};
        #pragma unroll
        for (int n = 0; n < 4; n++) {
            const unsigned short* kp = &Kb[(kt * 64 + n * 16 + col) * D_ + quad * 8];
            bf16x8 kf0 = *(const bf16x8*)kp;
            bf16x8 kf1 = *(const bf16x8*)(kp + 32);
            acc[n] = __builtin_amdgcn_mfma_f32_16x16x32_bf16(aq0, kf0, acc[n], 0, 0, 0);
            acc[n] = __builtin_amdgcn_mfma_f32_16x16x32_bf16(aq1, kf1, acc[n], 0, 0, 0);
        }
        if (kt == qt) {
            #pragma unroll
            for (int n = 0; n < 4; n++) {
                int kk = kt * 64 + n * 16 + col;
                #pragma unroll
                for (int r = 0; r < 4; r++) {
                    int q = q0 + w * 16 + quad * 4 + r;
                    if (kk > q) acc[n][r] = -1.0e30f;
                }
            }
        }
        #pragma unroll
        for (int r = 0; r < 4; r++) {
            lrun[r] += exp2f(acc[0][r]) + exp2f(acc[1][r]) +
                       exp2f(acc[2][r]) + exp2f(acc[3][r]);
        }
    }

    #pragma unroll
    for (int off = 1; off < 16; off <<= 1) {
        #pragma unroll
        for (int r = 0; r < 4; r++) lrun[r] += __shfl_xor(lrun[r], off, 64);
    }
    if (col == 0) {
        #pragma unroll
        for (int r = 0; r < 4; r++)
            atomicAdd(&lbuf[bh * S_ + q0 + w * 16 + quad * 4 + r], lrun[r]);
    }
}

// ---------------- fused flash attention: pass 2 only ----------------
// R6 structure minus pass 1 (denominators read from lbuf). The critical
// block's serial chain drops from 2 passes x (qt+1) tiles to 1 pass.
#define PST 78   // Pfh stride in shorts (39 words, odd -> conflict-free-ish)
__global__ __launch_bounds__(256) void attn_kernel(
    const unsigned short* __restrict__ Qh, const unsigned short* __restrict__ Kh,
    const unsigned short* __restrict__ VhT, const int* __restrict__ length,
    const float* __restrict__ lbuf,
    float* __restrict__ score, float* __restrict__ out2)
{
    __shared__ __align__(16) short Kbuf[2][2][64 * 72]; // [half][K=0/V=1]
    __shared__ __align__(16) short Pfh[64 * PST];       // P bf16 [q][k] (wave-local)

    int idx = blockIdx.x;
    int xcd = idx & 7;
    int slot = idx >> 3;
    int t = slot >> 2;
    int qt = (t < 16) ? t : 47 - t;
    int bh = xcd * 4 + (slot & 3);
    int b = bh >> 3, h = bh & 7;
    int q0 = qt * 64;
    int tid = threadIdx.x;
    int w = tid >> 6;
    int lane = tid & 63;
    int col = lane & 15;
    int quad = lane >> 4;
    int len = length[b];

    const unsigned short* Qb = Qh + (long)bh * S_ * D_;
    const unsigned short* Kb = Kh + (long)bh * S_ * D_;
    const unsigned short* Vtb = VhT + (long)bh * D_ * S_;
    float* scb = score + (long)bh * S_ * S_;

    // ---- full-block skip: every query row in this tile is masked ----
    if (q0 >= len) {
        f32x4 z = (f32x4){0.f, 0.f, 0.f, 0.f};
        for (int kt2 = 0; kt2 < 32; kt2++) {
            #pragma unroll
            for (int it = 0; it < 4; it++) {
                int idx2 = tid + it * 256;
                int rr = idx2 >> 4, cc = idx2 & 15;
                __builtin_nontemporal_store(z,
                    (f32x4*)&scb[(long)(q0 + rr) * S_ + kt2 * 64 + cc * 4]);
            }
        }
        #pragma unroll
        for (int it = 0; it < 4; it++) {
            int idx2 = tid + it * 256;
            int rr = idx2 >> 4, cc = idx2 & 15;
            *(f32x4*)&out2[((long)(b * S_ + q0 + rr)) * 512 + h * 64 + cc * 4] = z;
        }
        return;
    }

    int srow_ = tid >> 2, sc16_ = (tid & 3) * 16;   // staging coords

    // Q A-fragments direct from global (wave-contiguous, one-time)
    int arow = w * 16 + col;
    bf16x8 aq0 = *(const bf16x8*)&Qb[(q0 + arow) * D_ + quad * 8];
    bf16x8 aq1 = *(const bf16x8*)&Qb[(q0 + arow) * D_ + 32 + quad * 8];

    // denominators from lbuf (computed by lsum_kernel)
    float linv[4];
    {
        const float* lb = &lbuf[bh * S_ + q0 + w * 16 + quad * 4];
        #pragma unroll
        for (int r = 0; r < 4; r++) linv[r] = 1.0f / lb[r];
    }

    f32x4 oacc[4];
    #pragma unroll
    for (int n = 0; n < 4; n++) oacc[n] = (f32x4){0.f, 0.f, 0.f, 0.f};

    int prow = w * 16 + quad * 4;
    int rlo = lane >> 4;          // 0..3
    int c4 = (lane & 15) * 4;     // float offset in row

#define STAGE2(HALF, KT) do { \
    *(uint4*)&Kbuf[HALF][0][srow_ * 72 + sc16_] = \
        *(const uint4*)&Kb[((KT) * 64 + srow_) * D_ + sc16_]; \
    *(uint4*)&Kbuf[HALF][0][srow_ * 72 + sc16_ + 8] = \
        *(const uint4*)&Kb[((KT) * 64 + srow_) * D_ + sc16_ + 8]; \
    *(uint4*)&Kbuf[HALF][1][srow_ * 72 + sc16_] = \
        *(const uint4*)&Vtb[srow_ * S_ + (KT) * 64 + sc16_]; \
    *(uint4*)&Kbuf[HALF][1][srow_ * 72 + sc16_ + 8] = \
        *(const uint4*)&Vtb[srow_ * S_ + (KT) * 64 + sc16_ + 8]; \
} while (0)

#define TILE2(HALF, KT) do { \
    f32x4 acc[4]; \
    _Pragma("unroll") \
    for (int n = 0; n < 4; n++) acc[n] = (f32x4){0.f, 0.f, 0.f, 0.f}; \
    _Pragma("unroll") \
    for (int n = 0; n < 4; n++) { \
        bf16x8 b0 = *(const bf16x8*)&Kbuf[HALF][0][(n * 16 + col) * 72 + quad * 8]; \
        acc[n] = __builtin_amdgcn_mfma_f32_16x16x32_bf16(aq0, b0, acc[n], 0, 0, 0); \
        bf16x8 b1 = *(const bf16x8*)&Kbuf[HALF][0][(n * 16 + col) * 72 + 32 + quad * 8]; \
        acc[n] = __builtin_amdgcn_mfma_f32_16x16x32_bf16(aq1, b1, acc[n], 0, 0, 0); \
    } \
    bool diag = ((KT) == qt); \
    _Pragma("unroll") \
    for (int n = 0; n < 4; n++) { \
        int kk = (KT) * 64 + n * 16 + col; \
        _Pragma("unroll") \
        for (int r = 0; r < 4; r++) { \
            int q = q0 + prow + r; \
            float pv = exp2f(acc[n][r]) * linv[r]; \
            if (q >= len || (diag && kk > q)) pv = 0.f; \
            Pfh[(prow + r) * PST + n * 16 + col] = (short)f2bf(pv); \
        } \
    } \
    bf16x8 pa0 = *(const bf16x8*)&Pfh[(w * 16 + col) * PST + quad * 8]; \
    bf16x8 pa1 = *(const bf16x8*)&Pfh[(w * 16 + col) * PST + 32 + quad * 8]; \
    _Pragma("unroll") \
    for (int n = 0; n < 4; n++) { \
        bf16x8 vv0 = *(const bf16x8*)&Kbuf[HALF][1][(n * 16 + col) * 72 + quad * 8]; \
        oacc[n] = __builtin_amdgcn_mfma_f32_16x16x32_bf16(pa0, vv0, oacc[n], 0, 0, 0); \
        bf16x8 vv1 = *(const bf16x8*)&Kbuf[HALF][1][(n * 16 + col) * 72 + 32 + quad * 8]; \
        oacc[n] = __builtin_amdgcn_mfma_f32_16x16x32_bf16(pa1, vv1, oacc[n], 0, 0, 0); \
    } \
    _Pragma("unroll") \
    for (int j = 0; j < 4; j++) { \
        int row = w * 16 + j * 4 + rlo; \
        uint2 pk = *(const uint2*)&Pfh[row * PST + c4]; \
        f32x4 v; \
        v[0] = bf2f((unsigned short)(pk.x & 0xFFFFu)); \
        v[1] = bf2f((unsigned short)(pk.x >> 16)); \
        v[2] = bf2f((unsigned short)(pk.y & 0xFFFFu)); \
        v[3] = bf2f((unsigned short)(pk.y >> 16)); \
        __builtin_nontemporal_store(v, \
            (f32x4*)&scb[(long)(q0 + row) * S_ + (KT) * 64 + c4]); \
    } \
} while (0)

    STAGE2(0, 0);
    __syncthreads();
    {
        int kt = 0;
        while (true) {
            if (kt < qt) STAGE2(1, kt + 1);
            TILE2(0, kt);
            __syncthreads();
            kt++; if (kt > qt) break;
            if (kt < qt) STAGE2(0, kt + 1);
            TILE2(1, kt);
            __syncthreads();
            kt++; if (kt > qt) break;
        }
    }
#undef STAGE2
#undef TILE2

    // out2[b][s][h*64+dv]
    #pragma unroll
    for (int n = 0; n < 4; n++) {
        #pragma unroll
        for (int r = 0; r < 4; r++) {
            int q = q0 + w * 16 + quad * 4 + r;
            out2[((long)(b * S_ + q)) * 512 + h * 64 + n * 16 + col] = oacc[n][r];
        }
    }

    // zero the strictly-above-diagonal tiles (NT, coalesced)
    f32x4 z = (f32x4){0.f, 0.f, 0.f, 0.f};
    for (int kt2 = qt + 1; kt2 < 32; kt2++) {
        #pragma unroll
        for (int it = 0; it < 4; it++) {
            int idx2 = tid + it * 256;
            int rr = idx2 >> 4, cc = idx2 & 15;
            __builtin_nontemporal_store(z,
                (f32x4*)&scb[(long)(q0 + rr) * S_ + kt2 * 64 + cc * 4]);
        }
    }
}

// ---------------- MLP head (f32x4 dot on packed w1T4) ----------------
__global__ __launch_bounds__(256) void mlp_kernel(
    const float* __restrict__ out2, const float* __restrict__ w1T4,
    const float* __restrict__ b1, const float* __restrict__ w2,
    const float* __restrict__ b2, float* __restrict__ out3)
{
    __shared__ __align__(16) float xr[2048];
    int sg0 = blockIdx.x * 4;
    int tid = threadIdx.x;
    for (int i = tid; i < 512; i += 256)
        *(f32x4*)&xr[i * 4] = *(const f32x4*)&out2[(long)sg0 * 512 + i * 4];
    __syncthreads();

    int sl = tid >> 6, d = tid & 63;
    float acc = 0.f;
    #pragma unroll 4
    for (int jb = 0; jb < 128; jb++) {
        f32x4 xv = *(const f32x4*)&xr[sl * 512 + jb * 4];
        f32x4 wv = *(const f32x4*)&w1T4[jb * 256 + d * 4];
        acc += xv[0] * wv[0] + xv[1] * wv[1] + xv[2] * wv[2] + xv[3] * wv[3];
    }
    float hval = fmaxf(acc + b1[d], 0.f);
    float p = hval * w2[d];
    #pragma unroll
    for (int off = 32; off > 0; off >>= 1) p += __shfl_xor(p, off, 64);
    if (d == 0) out3[sg0 + sl] = p + b2[0];
}

// ---------------- launcher ----------------
extern "C" void kernel_launch(void* const* d_in, const int* in_sizes, int n_in,
                              void* d_out, int out_size, void* d_ws, size_t ws_size,
                              hipStream_t stream) {
    const float* x      = (const float*)d_in[0];
    const int*   length = (const int*)  d_in[1];
    const float* wq     = (const float*)d_in[2];
    const float* bq     = (const float*)d_in[3];
    const float* wk     = (const float*)d_in[4];
    const float* bk     = (const float*)d_in[5];
    const float* wv     = (const float*)d_in[6];
    const float* bv     = (const float*)d_in[7];
    const float* w1     = (const float*)d_in[8];
    const float* b1     = (const float*)d_in[9];
    const float* w2     = (const float*)d_in[10];
    const float* b2     = (const float*)d_in[11];

    float* out3  = (float*)d_out;
    float* score = (float*)d_out + 8192;   // (B,H,S,S) follows (B,S,1)

    float* ws  = (float*)d_ws;
    unsigned short* xh     = (unsigned short*)ws;  ws += 524288;
    unsigned short* wPackQ = (unsigned short*)ws;  ws += 98304;
    unsigned short* wPackK = (unsigned short*)ws;  ws += 98304;
    unsigned short* wPackV = (unsigned short*)ws;  ws += 32768;
    float* w1T4 = ws;  ws += 32768;
    float* lbuf = ws;  ws += 65536;
    unsigned short* Qh  = (unsigned short*)ws;  ws += 2097152;
    unsigned short* Kh  = (unsigned short*)ws;  ws += 2097152;
    unsigned short* VhT = (unsigned short*)ws;  ws += 2097152;
    float* o2  = ws;  ws += 4194304;

    hipLaunchKernelGGL(prep_kernel, dim3(3200), dim3(256), 0, stream,
                       x, wq, wk, wv, w1, xh, wPackQ, wPackK, wPackV, w1T4, lbuf);
    hipLaunchKernelGGL(qkv_kernel, dim3(16, 8, 4), dim3(256), 0, stream,
                       xh, wPackQ, wPackK, wPackV, bq, bk, bv, Qh, Kh, VhT);
    hipLaunchKernelGGL(lsum_kernel, dim3(32, 32, 8), dim3(256), 0, stream,
                       Qh, Kh, length, lbuf);
    hipLaunchKernelGGL(attn_kernel, dim3(1024), dim3(256), 0, stream,
                       Qh, Kh, VhT, length, lbuf, score, o2);
    hipLaunchKernelGGL(mlp_kernel, dim3(2048), dim3(256), 0, stream,
                       o2, w1T4, b1, w2, b2, out3);
}

// Round 11
// 634.051 us; speedup vs baseline: 1.0764x; 1.0646x over previous
//
#include <hip/hip_runtime.h>

#define S_ 2048
#define C_ 128
#define B_ 4
#define H_ 8
#define D_ 64

typedef __attribute__((ext_vector_type(8))) short bf16x8;
typedef __attribute__((ext_vector_type(4))) float f32x4;

__device__ inline unsigned short f2bf(float f) {
    union { float f; unsigned int u; } c; c.f = f;
    unsigned int u = c.u;
    unsigned int r = (u + 0x7FFFu + ((u >> 16) & 1u)) >> 16;
    return (unsigned short)r;
}
__device__ inline float bf2f(unsigned short s) {
    union { unsigned int u; float f; } c; c.u = ((unsigned int)s) << 16;
    return c.f;
}

// ---------------- prep: x->bf16 (float4), weights -> packed bf16, w1 -> w1T4 ----------------
__global__ __launch_bounds__(256) void prep_kernel(
    const float* __restrict__ x,
    const float* __restrict__ wq, const float* __restrict__ wk,
    const float* __restrict__ wv, const float* __restrict__ w1,
    unsigned short* __restrict__ xh,
    unsigned short* __restrict__ wPackQ, unsigned short* __restrict__ wPackK,
    unsigned short* __restrict__ wPackV, float* __restrict__ w1T4)
{
    int idx = blockIdx.x * 256 + threadIdx.x;
    if (idx < 262144) {                        // x: 4 elements per thread
        float4 v = *(const float4*)&x[idx * 4];
        ushort4 o;
        o.x = f2bf(v.x); o.y = f2bf(v.y); o.z = f2bf(v.z); o.w = f2bf(v.w);
        *(ushort4*)&xh[idx * 4] = o;
    } else if (idx < 458752) {                 // wPackQ: i = t*65536 + o*128 + c
        int i = idx - 262144;
        int t = i >> 16, r = i & 65535;
        int o = r >> 7, c = r & 127;
        wPackQ[i] = f2bf(wq[o * 384 + c * 3 + t]);
    } else if (idx < 655360) {
        int i = idx - 458752;
        int t = i >> 16, r = i & 65535;
        int o = r >> 7, c = r & 127;
        wPackK[i] = f2bf(wk[o * 384 + c * 3 + t]);
    } else if (idx < 720896) {
        int i = idx - 655360;
        wPackV[i] = f2bf(wv[i]);
    } else if (idx < 753664) {
        int i = idx - 720896;
        int jj = i & 3, d = (i >> 2) & 63, jb = i >> 8;
        w1T4[i] = w1[d * 512 + jb * 4 + jj];
    }
}

// ---------------- QKV projection via bf16 MFMA (Q,K,V fused per block) ----------------
// Q is scaled by 0.125 * log2(e) so attention can use exp2 directly.
__global__ __launch_bounds__(256) void qkv_kernel(
    const unsigned short* __restrict__ xh,
    const unsigned short* __restrict__ wPackQ, const unsigned short* __restrict__ wPackK,
    const unsigned short* __restrict__ wPackV,
    const float* __restrict__ bq, const float* __restrict__ bk,
    const float* __restrict__ bv,
    unsigned short* __restrict__ Qh, unsigned short* __restrict__ Kh,
    unsigned short* __restrict__ VhT)
{
    __shared__ __align__(16) short xs[130 * 136];
    __shared__ __align__(16) short ws[64 * 136];

    int s0 = blockIdx.x * 128;
    int h = blockIdx.y;
    int b = blockIdx.z;
    int bh = b * H_ + h;
    int tid = threadIdx.x;
    int w = tid >> 6;
    int lane = tid & 63;
    int col = lane & 15;
    int quad = lane >> 4;

    for (int i = tid; i < 2080; i += 256) {
        int row = i >> 4, c8 = (i & 15) << 3;
        int s = s0 - 2 + row;
        uint4 v = {0u, 0u, 0u, 0u};
        if (s >= 0) v = *(const uint4*)&xh[((long)b * S_ + s) * C_ + c8];
        *(uint4*)&xs[row * 136 + c8] = v;
    }

    for (int sec = 0; sec < 3; sec++) {
        const unsigned short* wsel = (sec == 0) ? wPackQ : (sec == 1) ? wPackK : wPackV;
        int tlo = (sec == 2) ? 2 : 0;

        f32x4 acc[2][4];
        #pragma unroll
        for (int rt = 0; rt < 2; rt++)
            #pragma unroll
            for (int nt = 0; nt < 4; nt++) acc[rt][nt] = (f32x4){0.f, 0.f, 0.f, 0.f};

        for (int t = tlo; t < 3; t++) {
            if (!(sec == 0 && t == 0)) __syncthreads();
            long wbase = (sec == 2) ? ((long)h * 8192)
                                    : ((long)t * 65536 + (long)h * 8192);
            for (int i = tid; i < 1024; i += 256) {
                int row = i >> 4, c8 = (i & 15) << 3;
                *(uint4*)&ws[row * 136 + c8] = *(const uint4*)&wsel[wbase + row * 128 + c8];
            }
            __syncthreads();

            #pragma unroll
            for (int kc = 0; kc < 4; kc++) {
                int ko = kc * 32 + quad * 8;
                bf16x8 a0 = *(const bf16x8*)&xs[(w * 32 + col + t) * 136 + ko];
                bf16x8 a1 = *(const bf16x8*)&xs[(w * 32 + 16 + col + t) * 136 + ko];
                #pragma unroll
                for (int nt = 0; nt < 4; nt++) {
                    bf16x8 bfr = *(const bf16x8*)&ws[(nt * 16 + col) * 136 + ko];
                    acc[0][nt] = __builtin_amdgcn_mfma_f32_16x16x32_bf16(a0, bfr, acc[0][nt], 0, 0, 0);
                    acc[1][nt] = __builtin_amdgcn_mfma_f32_16x16x32_bf16(a1, bfr, acc[1][nt], 0, 0, 0);
                }
            }
        }

        if (sec == 0) {
            #pragma unroll
            for (int nt = 0; nt < 4; nt++) {
                float bias = bq[h * 64 + nt * 16 + col];
                #pragma unroll
                for (int rt = 0; rt < 2; rt++)
                    #pragma unroll
                    for (int r = 0; r < 4; r++) {
                        int s = s0 + w * 32 + rt * 16 + quad * 4 + r;
                        Qh[((long)bh * S_ + s) * D_ + nt * 16 + col] =
                            f2bf((acc[rt][nt][r] + bias) * 0.18033688011112042f); // 0.125*log2(e)
                    }
            }
        } else if (sec == 1) {
            #pragma unroll
            for (int nt = 0; nt < 4; nt++) {
                float bias = bk[h * 64 + nt * 16 + col];
                #pragma unroll
                for (int rt = 0; rt < 2; rt++)
                    #pragma unroll
                    for (int r = 0; r < 4; r++) {
                        int s = s0 + w * 32 + rt * 16 + quad * 4 + r;
                        Kh[((long)bh * S_ + s) * D_ + nt * 16 + col] =
                            f2bf(acc[rt][nt][r] + bias);
                    }
            }
        } else {
            __syncthreads();
            #pragma unroll
            for (int nt = 0; nt < 4; nt++) {
                float bias = bv[h * 64 + nt * 16 + col];
                #pragma unroll
                for (int rt = 0; rt < 2; rt++)
                    #pragma unroll
                    for (int r = 0; r < 4; r++) {
                        int sl = w * 32 + rt * 16 + quad * 4 + r;
                        ws[(nt * 16 + col) * 136 + sl] =
                            (short)f2bf(fmaxf(acc[rt][nt][r] + bias, 0.f));
                    }
            }
            __syncthreads();
            for (int i = tid; i < 1024; i += 256) {
                int row = i >> 4, c8 = (i & 15) << 3;
                *(uint4*)&VhT[((long)bh * D_ + row) * S_ + s0 + c8] =
                    *(const uint4*)&ws[row * 136 + c8];
            }
        }
    }
}

// ---------------- fused flash attention ----------------
// R6 structure (best-measured: 634.3us). Single change vs R6: the pass-2
// P-pack uses v_cvt_pk_bf16_f32 (2 conversions/inst, RNE — bit-identical
// to f2bf) instead of 4-5-op manual rounding: ~72 -> ~16 VALU per n-loop.
#define PST 78   // Pfh stride in shorts (39 words, odd -> conflict-free-ish)
__global__ __launch_bounds__(256) void attn_kernel(
    const unsigned short* __restrict__ Qh, const unsigned short* __restrict__ Kh,
    const unsigned short* __restrict__ VhT, const int* __restrict__ length,
    float* __restrict__ score, float* __restrict__ out2)
{
    __shared__ __align__(16) short Kbuf[2][2][64 * 72]; // [half][K=0/V=1]
    __shared__ __align__(16) short Pfh[64 * PST];       // P bf16 [q][k] (wave-local)

    int idx = blockIdx.x;
    int xcd = idx & 7;
    int slot = idx >> 3;
    int t = slot >> 2;
    int qt = (t < 16) ? t : 47 - t;
    int bh = xcd * 4 + (slot & 3);
    int b = bh >> 3, h = bh & 7;
    int q0 = qt * 64;
    int tid = threadIdx.x;
    int w = tid >> 6;
    int lane = tid & 63;
    int col = lane & 15;
    int quad = lane >> 4;
    int len = length[b];

    const unsigned short* Qb = Qh + (long)bh * S_ * D_;
    const unsigned short* Kb = Kh + (long)bh * S_ * D_;
    const unsigned short* Vtb = VhT + (long)bh * D_ * S_;
    float* scb = score + (long)bh * S_ * S_;

    // ---- full-block skip: every query row in this tile is masked ----
    if (q0 >= len) {
        f32x4 z = (f32x4){0.f, 0.f, 0.f, 0.f};
        for (int kt2 = 0; kt2 < 32; kt2++) {
            #pragma unroll
            for (int it = 0; it < 4; it++) {
                int idx2 = tid + it * 256;
                int rr = idx2 >> 4, cc = idx2 & 15;
                __builtin_nontemporal_store(z,
                    (f32x4*)&scb[(long)(q0 + rr) * S_ + kt2 * 64 + cc * 4]);
            }
        }
        #pragma unroll
        for (int it = 0; it < 4; it++) {
            int idx2 = tid + it * 256;
            int rr = idx2 >> 4, cc = idx2 & 15;
            *(f32x4*)&out2[((long)(b * S_ + q0 + rr)) * 512 + h * 64 + cc * 4] = z;
        }
        return;
    }

    int srow_ = tid >> 2, sc16_ = (tid & 3) * 16;   // staging coords

    // Q A-fragments direct from global (wave-contiguous, one-time)
    int arow = w * 16 + col;
    bf16x8 aq0 = *(const bf16x8*)&Qb[(q0 + arow) * D_ + quad * 8];
    bf16x8 aq1 = *(const bf16x8*)&Qb[(q0 + arow) * D_ + 32 + quad * 8];

    // ---- pass 1: l = sum(exp2(s')) per row, K double-buffered ----
    float lrun[4];
    #pragma unroll
    for (int r = 0; r < 4; r++) lrun[r] = 0.f;

    {   // prologue: stage K tile 0
        *(uint4*)&Kbuf[0][0][srow_ * 72 + sc16_]     = *(const uint4*)&Kb[srow_ * D_ + sc16_];
        *(uint4*)&Kbuf[0][0][srow_ * 72 + sc16_ + 8] = *(const uint4*)&Kb[srow_ * D_ + sc16_ + 8];
    }
    __syncthreads();

    for (int kt = 0; kt <= qt; kt++) {
        int buf = kt & 1;
        if (kt < qt) {
            *(uint4*)&Kbuf[1 - buf][0][srow_ * 72 + sc16_] =
                *(const uint4*)&Kb[((kt + 1) * 64 + srow_) * D_ + sc16_];
            *(uint4*)&Kbuf[1 - buf][0][srow_ * 72 + sc16_ + 8] =
                *(const uint4*)&Kb[((kt + 1) * 64 + srow_) * D_ + sc16_ + 8];
        }

        f32x4 acc[4];
        #pragma unroll
        for (int n = 0; n < 4; n++) acc[n] = (f32x4){0.f, 0.f, 0.f, 0.f};
        #pragma unroll
        for (int n = 0; n < 4; n++) {
            bf16x8 b0 = *(const bf16x8*)&Kbuf[buf][0][(n * 16 + col) * 72 + quad * 8];
            acc[n] = __builtin_amdgcn_mfma_f32_16x16x32_bf16(aq0, b0, acc[n], 0, 0, 0);
            bf16x8 b1 = *(const bf16x8*)&Kbuf[buf][0][(n * 16 + col) * 72 + 32 + quad * 8];
            acc[n] = __builtin_amdgcn_mfma_f32_16x16x32_bf16(aq1, b1, acc[n], 0, 0, 0);
        }
        if (kt == qt) {
            #pragma unroll
            for (int n = 0; n < 4; n++) {
                int kk = kt * 64 + n * 16 + col;
                #pragma unroll
                for (int r = 0; r < 4; r++) {
                    int q = q0 + w * 16 + quad * 4 + r;
                    if (kk > q) acc[n][r] = -1.0e30f;
                }
            }
        }
        #pragma unroll
        for (int r = 0; r < 4; r++) {
            lrun[r] += exp2f(acc[0][r]) + exp2f(acc[1][r]) +
                       exp2f(acc[2][r]) + exp2f(acc[3][r]);
        }
        __syncthreads();
    }

    #pragma unroll
    for (int off = 1; off < 16; off <<= 1) {
        #pragma unroll
        for (int r = 0; r < 4; r++) lrun[r] += __shfl_xor(lrun[r], off, 64);
    }
    float linv[4];
    #pragma unroll
    for (int r = 0; r < 4; r++) linv[r] = 1.0f / lrun[r];

    // ---- pass 2: recompute logits, bf16 P via cvt_pk, coalesced NT store, P@V ----
    f32x4 oacc[4];
    #pragma unroll
    for (int n = 0; n < 4; n++) oacc[n] = (f32x4){0.f, 0.f, 0.f, 0.f};

    int prow = w * 16 + quad * 4;
    int rlo = lane >> 4;          // 0..3
    int c4 = (lane & 15) * 4;     // float offset in row

#define STAGE2(HALF, KT) do { \
    *(uint4*)&Kbuf[HALF][0][srow_ * 72 + sc16_] = \
        *(const uint4*)&Kb[((KT) * 64 + srow_) * D_ + sc16_]; \
    *(uint4*)&Kbuf[HALF][0][srow_ * 72 + sc16_ + 8] = \
        *(const uint4*)&Kb[((KT) * 64 + srow_) * D_ + sc16_ + 8]; \
    *(uint4*)&Kbuf[HALF][1][srow_ * 72 + sc16_] = \
        *(const uint4*)&Vtb[srow_ * S_ + (KT) * 64 + sc16_]; \
    *(uint4*)&Kbuf[HALF][1][srow_ * 72 + sc16_ + 8] = \
        *(const uint4*)&Vtb[srow_ * S_ + (KT) * 64 + sc16_ + 8]; \
} while (0)

#define TILE2(HALF, KT) do { \
    f32x4 acc[4]; \
    _Pragma("unroll") \
    for (int n = 0; n < 4; n++) acc[n] = (f32x4){0.f, 0.f, 0.f, 0.f}; \
    _Pragma("unroll") \
    for (int n = 0; n < 4; n++) { \
        bf16x8 b0 = *(const bf16x8*)&Kbuf[HALF][0][(n * 16 + col) * 72 + quad * 8]; \
        acc[n] = __builtin_amdgcn_mfma_f32_16x16x32_bf16(aq0, b0, acc[n], 0, 0, 0); \
        bf16x8 b1 = *(const bf16x8*)&Kbuf[HALF][0][(n * 16 + col) * 72 + 32 + quad * 8]; \
        acc[n] = __builtin_amdgcn_mfma_f32_16x16x32_bf16(aq1, b1, acc[n], 0, 0, 0); \
    } \
    bool diag = ((KT) == qt); \
    _Pragma("unroll") \
    for (int n = 0; n < 4; n++) { \
        int kk = (KT) * 64 + n * 16 + col; \
        float p[4]; \
        _Pragma("unroll") \
        for (int r = 0; r < 4; r++) { \
            int q = q0 + prow + r; \
            float pv = exp2f(acc[n][r]) * linv[r]; \
            if (q >= len || (diag && kk > q)) pv = 0.f; \
            p[r] = pv; \
        } \
        unsigned int pk01, pk23; \
        asm("v_cvt_pk_bf16_f32 %0, %1, %2" : "=v"(pk01) : "v"(p[0]), "v"(p[1])); \
        asm("v_cvt_pk_bf16_f32 %0, %1, %2" : "=v"(pk23) : "v"(p[2]), "v"(p[3])); \
        int pcol = n * 16 + col; \
        Pfh[prow * PST + pcol]       = (short)(pk01 & 0xFFFFu); \
        Pfh[(prow + 1) * PST + pcol] = (short)(pk01 >> 16); \
        Pfh[(prow + 2) * PST + pcol] = (short)(pk23 & 0xFFFFu); \
        Pfh[(prow + 3) * PST + pcol] = (short)(pk23 >> 16); \
    } \
    bf16x8 pa0 = *(const bf16x8*)&Pfh[(w * 16 + col) * PST + quad * 8]; \
    bf16x8 pa1 = *(const bf16x8*)&Pfh[(w * 16 + col) * PST + 32 + quad * 8]; \
    _Pragma("unroll") \
    for (int n = 0; n < 4; n++) { \
        bf16x8 vv0 = *(const bf16x8*)&Kbuf[HALF][1][(n * 16 + col) * 72 + quad * 8]; \
        oacc[n] = __builtin_amdgcn_mfma_f32_16x16x32_bf16(pa0, vv0, oacc[n], 0, 0, 0); \
        bf16x8 vv1 = *(const bf16x8*)&Kbuf[HALF][1][(n * 16 + col) * 72 + 32 + quad * 8]; \
        oacc[n] = __builtin_amdgcn_mfma_f32_16x16x32_bf16(pa1, vv1, oacc[n], 0, 0, 0); \
    } \
    _Pragma("unroll") \
    for (int j = 0; j < 4; j++) { \
        int row = w * 16 + j * 4 + rlo; \
        uint2 pk = *(const uint2*)&Pfh[row * PST + c4]; \
        f32x4 v; \
        v[0] = bf2f((unsigned short)(pk.x & 0xFFFFu)); \
        v[1] = bf2f((unsigned short)(pk.x >> 16)); \
        v[2] = bf2f((unsigned short)(pk.y & 0xFFFFu)); \
        v[3] = bf2f((unsigned short)(pk.y >> 16)); \
        __builtin_nontemporal_store(v, \
            (f32x4*)&scb[(long)(q0 + row) * S_ + (KT) * 64 + c4]); \
    } \
} while (0)

    STAGE2(0, 0);
    __syncthreads();
    {
        int kt = 0;
        while (true) {
            if (kt < qt) STAGE2(1, kt + 1);
            TILE2(0, kt);
            __syncthreads();
            kt++; if (kt > qt) break;
            if (kt < qt) STAGE2(0, kt + 1);
            TILE2(1, kt);
            __syncthreads();
            kt++; if (kt > qt) break;
        }
    }
#undef STAGE2
#undef TILE2

    // out2[b][s][h*64+dv]
    #pragma unroll
    for (int n = 0; n < 4; n++) {
        #pragma unroll
        for (int r = 0; r < 4; r++) {
            int q = q0 + w * 16 + quad * 4 + r;
            out2[((long)(b * S_ + q)) * 512 + h * 64 + n * 16 + col] = oacc[n][r];
        }
    }

    // zero the strictly-above-diagonal tiles (NT, coalesced)
    f32x4 z = (f32x4){0.f, 0.f, 0.f, 0.f};
    for (int kt2 = qt + 1; kt2 < 32; kt2++) {
        #pragma unroll
        for (int it = 0; it < 4; it++) {
            int idx2 = tid + it * 256;
            int rr = idx2 >> 4, cc = idx2 & 15;
            __builtin_nontemporal_store(z,
                (f32x4*)&scb[(long)(q0 + rr) * S_ + kt2 * 64 + cc * 4]);
        }
    }
}

// ---------------- MLP head (f32x4 dot on packed w1T4) ----------------
__global__ __launch_bounds__(256) void mlp_kernel(
    const float* __restrict__ out2, const float* __restrict__ w1T4,
    const float* __restrict__ b1, const float* __restrict__ w2,
    const float* __restrict__ b2, float* __restrict__ out3)
{
    __shared__ __align__(16) float xr[2048];
    int sg0 = blockIdx.x * 4;
    int tid = threadIdx.x;
    for (int i = tid; i < 512; i += 256)
        *(f32x4*)&xr[i * 4] = *(const f32x4*)&out2[(long)sg0 * 512 + i * 4];
    __syncthreads();

    int sl = tid >> 6, d = tid & 63;
    float acc = 0.f;
    #pragma unroll 4
    for (int jb = 0; jb < 128; jb++) {
        f32x4 xv = *(const f32x4*)&xr[sl * 512 + jb * 4];
        f32x4 wv = *(const f32x4*)&w1T4[jb * 256 + d * 4];
        acc += xv[0] * wv[0] + xv[1] * wv[1] + xv[2] * wv[2] + xv[3] * wv[3];
    }
    float hval = fmaxf(acc + b1[d], 0.f);
    float p = hval * w2[d];
    #pragma unroll
    for (int off = 32; off > 0; off >>= 1) p += __shfl_xor(p, off, 64);
    if (d == 0) out3[sg0 + sl] = p + b2[0];
}

// ---------------- launcher ----------------
extern "C" void kernel_launch(void* const* d_in, const int* in_sizes, int n_in,
                              void* d_out, int out_size, void* d_ws, size_t ws_size,
                              hipStream_t stream) {
    const float* x      = (const float*)d_in[0];
    const int*   length = (const int*)  d_in[1];
    const float* wq     = (const float*)d_in[2];
    const float* bq     = (const float*)d_in[3];
    const float* wk     = (const float*)d_in[4];
    const float* bk     = (const float*)d_in[5];
    const float* wv     = (const float*)d_in[6];
    const float* bv     = (const float*)d_in[7];
    const float* w1     = (const float*)d_in[8];
    const float* b1     = (const float*)d_in[9];
    const float* w2     = (const float*)d_in[10];
    const float* b2     = (const float*)d_in[11];

    float* out3  = (float*)d_out;
    float* score = (float*)d_out + 8192;   // (B,H,S,S) follows (B,S,1)

    float* ws  = (float*)d_ws;
    unsigned short* xh     = (unsigned short*)ws;  ws += 524288;
    unsigned short* wPackQ = (unsigned short*)ws;  ws += 98304;
    unsigned short* wPackK = (unsigned short*)ws;  ws += 98304;
    unsigned short* wPackV = (unsigned short*)ws;  ws += 32768;
    float* w1T4 = ws;  ws += 32768;
    unsigned short* Qh  = (unsigned short*)ws;  ws += 2097152;
    unsigned short* Kh  = (unsigned short*)ws;  ws += 2097152;
    unsigned short* VhT = (unsigned short*)ws;  ws += 2097152;
    float* o2  = ws;  ws += 4194304;

    hipLaunchKernelGGL(prep_kernel, dim3(2944), dim3(256), 0, stream,
                       x, wq, wk, wv, w1, xh, wPackQ, wPackK, wPackV, w1T4);
    hipLaunchKernelGGL(qkv_kernel, dim3(16, 8, 4), dim3(256), 0, stream,
                       xh, wPackQ, wPackK, wPackV, bq, bk, bv, Qh, Kh, VhT);
    hipLaunchKernelGGL(attn_kernel, dim3(1024), dim3(256), 0, stream,
                       Qh, Kh, VhT, length, score, o2);
    hipLaunchKernelGGL(mlp_kernel, dim3(2048), dim3(256), 0, stream,
                       o2, w1T4, b1, w2, b2, out3);
}